// Round 11
// baseline (317.043 us; speedup 1.0000x reference)
//
#include <hip/hip_runtime.h>
#include <hip/hip_bf16.h>

typedef __attribute__((ext_vector_type(8))) short bf16x8;
typedef __attribute__((ext_vector_type(4))) float f32x4;

#define MFMA16(a,b,c) __builtin_amdgcn_mfma_f32_16x16x32_bf16(a,b,c,0,0,0)

__device__ __forceinline__ unsigned short f2bf(float f){
  __hip_bfloat16 h = __float2bfloat16(f);
  unsigned short r;
  __builtin_memcpy(&r, &h, 2);
  return r;
}
__device__ __forceinline__ float bf2f(unsigned short u){
  return __uint_as_float(((unsigned int)u) << 16);
}
__device__ __forceinline__ bf16x8 cvt8(float4 a, float4 b){
  bf16x8 t;
  t[0] = (short)f2bf(a.x); t[1] = (short)f2bf(a.y);
  t[2] = (short)f2bf(a.z); t[3] = (short)f2bf(a.w);
  t[4] = (short)f2bf(b.x); t[5] = (short)f2bf(b.y);
  t[6] = (short)f2bf(b.z); t[7] = (short)f2bf(b.w);
  return t;
}

// ---------------- qkvg projection GEMM: f32 inputs, convert in-register ----------------
// R6-proven body. wave tile 32x64; block 64x128. B matrix selected by bx>>3.
// Aux block (blockIdx.x==32, y==0): wz prep (wz'=wz*w bf16, c1, c2).
__global__ __launch_bounds__(256) void gemm_qkvg(
    const float* __restrict__ s, const float* __restrict__ wq,
    const float* __restrict__ wk, const float* __restrict__ wv,
    const float* __restrict__ wg, const float* __restrict__ bq,
    const float* __restrict__ wz, const float* __restrict__ znw,
    const float* __restrict__ znb,
    unsigned short* __restrict__ qb, unsigned short* __restrict__ kb,
    unsigned short* __restrict__ vT, unsigned short* __restrict__ gb,
    unsigned short* __restrict__ wzp, float* __restrict__ c12)
{
  if (blockIdx.x == 32) {
    if (blockIdx.y != 0) return;
    __shared__ float r1[256], r2[256];
    int t = threadIdx.x; int h = t >> 4; int k0 = (t & 15) * 8;
    float p1 = 0.f, p2 = 0.f;
    for (int e = 0; e < 8; e++) {
      float wvv = wz[h*128 + k0 + e];
      float w = znw[k0 + e], b = znb[k0 + e];
      wzp[h*128 + k0 + e] = f2bf(wvv * w);
      p1 += wvv * w; p2 += wvv * b;
    }
    r1[t] = p1; r2[t] = p2;
    __syncthreads();
    if ((t & 15) == 0) {
      float s1 = 0.f, s2 = 0.f;
      for (int i = 0; i < 16; i++) { s1 += r1[t + i]; s2 += r2[t + i]; }
      c12[2*h] = s1; c12[2*h + 1] = s2;
    }
    return;
  }
  int lane = threadIdx.x & 63;
  int w = threadIdx.x >> 6;
  int lr = lane & 15, lg = lane >> 4;
  int row0 = blockIdx.y * 64 + (w & 1) * 32;
  int bx = blockIdx.x;
  const float* Bm = (bx < 8) ? wq : (bx < 16) ? wk : (bx < 24) ? wv : wg;
  int colL = (bx & 7) * 128 + (w >> 1) * 64;
  int colG = bx * 128 + (w >> 1) * 64;
  f32x4 acc[2][4] = {};
  for (int kk = 0; kk < 1024; kk += 32) {
    bf16x8 af[2], bfr[4];
    #pragma unroll
    for (int t = 0; t < 2; t++) {
      const float* p = s + (size_t)(row0 + t*16 + lr)*1024 + kk + lg*8;
      af[t] = cvt8(*(const float4*)p, *(const float4*)(p + 4));
    }
    #pragma unroll
    for (int t = 0; t < 4; t++) {
      const float* p = Bm + (size_t)(colL + t*16 + lr)*1024 + kk + lg*8;
      bfr[t] = cvt8(*(const float4*)p, *(const float4*)(p + 4));
    }
    #pragma unroll
    for (int a = 0; a < 2; a++)
      #pragma unroll
      for (int b = 0; b < 4; b++)
        acc[a][b] = MFMA16(af[a], bfr[b], acc[a][b]);
  }
  #pragma unroll
  for (int a = 0; a < 2; a++)
    #pragma unroll
    for (int b = 0; b < 4; b++)
      #pragma unroll
      for (int r = 0; r < 4; r++) {
        int m = row0 + a*16 + lg*4 + r;
        int n = colG + b*16 + lr;
        float v = acc[a][b][r];
        if (n < 1024)      { v = (v + bq[n]) * 0.125f; qb[(size_t)m*1024 + n] = f2bf(v); }
        else if (n < 2048) { kb[(size_t)m*1024 + (n-1024)] = f2bf(v); }
        else if (n < 3072) { vT[(size_t)(n-2048)*1024 + m] = f2bf(v); }
        else               { float sg = 1.f / (1.f + __expf(-v)); gb[(size_t)m*1024 + (n-3072)] = f2bf(sg); }
      }
}

// ---------------- fused bias + attention (R10 body, unchanged) ----------------
__global__ __launch_bounds__(1024, 4) void fused_attn(
    const unsigned short* __restrict__ qb, const unsigned short* __restrict__ kb,
    const unsigned short* __restrict__ vT, const float* __restrict__ z,
    const unsigned short* __restrict__ wzp, const float* __restrict__ c12,
    float* __restrict__ op, float* __restrict__ ml, float* __restrict__ ll)
{
  __shared__ float biasT[16][17][68];        // [h][q-local(pad17)][j-local]
  __shared__ unsigned short P[16][1024];     // per-wave P bounce, XOR-swizzled
  int w = threadIdx.x >> 6;                  // wave id = head = owned q-row
  int lane = threadIdx.x & 63;
  int jl = lane & 15, g = lane >> 4;
  int q0 = blockIdx.x * 16;
  int s = blockIdx.y;                        // j-quarter
  int h = w;
  unsigned short* Pw = P[w];

  bf16x8 af[4];
  #pragma unroll
  for (int mk = 0; mk < 4; mk++)
    af[mk] = *(const bf16x8*)(wzp + jl*128 + mk*32 + g*8);
  bf16x8 aq[2];
  #pragma unroll
  for (int kh = 0; kh < 2; kh++)
    aq[kh] = *(const bf16x8*)(qb + (size_t)(q0 + jl)*1024 + h*64 + kh*32 + g*8);
  float c1r[4], c2r[4];
  #pragma unroll
  for (int r = 0; r < 4; r++) {
    c1r[r] = c12[2*(g*4 + r)];
    c2r[r] = c12[2*(g*4 + r) + 1];
  }

  f32x4 od[4] = {};
  float m = -1e30f, ss = 0.f;

  #pragma unroll 1
  for (int t = 0; t < 4; t++) {
    int jt = s*256 + t*64;

    // ---------- phase A: bias fill for q-row q0+w, j in [jt, jt+64) ----------
    #pragma unroll 1
    for (int it = 0; it < 4; it++) {
      int j = jt + it*16 + jl;
      const float* zp = z + ((size_t)(q0 + w)*1024 + j)*128;
      bf16x8 tf[4];
      float sum = 0.f, sq = 0.f;
      #pragma unroll
      for (int mk = 0; mk < 4; mk++) {
        float4 a = *(const float4*)(zp + mk*32 + g*8);
        float4 b = *(const float4*)(zp + mk*32 + g*8 + 4);
        sum += a.x + a.y + a.z + a.w + b.x + b.y + b.z + b.w;
        sq = fmaf(a.x, a.x, fmaf(a.y, a.y, fmaf(a.z, a.z, fmaf(a.w, a.w, sq))));
        sq = fmaf(b.x, b.x, fmaf(b.y, b.y, fmaf(b.z, b.z, fmaf(b.w, b.w, sq))));
        bf16x8 tv;
        tv[0] = (short)f2bf(a.x); tv[1] = (short)f2bf(a.y);
        tv[2] = (short)f2bf(a.z); tv[3] = (short)f2bf(a.w);
        tv[4] = (short)f2bf(b.x); tv[5] = (short)f2bf(b.y);
        tv[6] = (short)f2bf(b.z); tv[7] = (short)f2bf(b.w);
        tf[mk] = tv;
      }
      sum += __shfl_xor(sum, 16); sum += __shfl_xor(sum, 32);
      sq  += __shfl_xor(sq, 16);  sq  += __shfl_xor(sq, 32);
      float mu = sum * (1.f/128.f);
      float rs = rsqrtf(sq * (1.f/128.f) - mu*mu + 1e-5f);
      f32x4 D = {0.f, 0.f, 0.f, 0.f};
      #pragma unroll
      for (int mk = 0; mk < 4; mk++)
        D = MFMA16(af[mk], tf[mk], D);
      #pragma unroll
      for (int r = 0; r < 4; r++)
        biasT[g*4 + r][w][it*16 + jl] = rs*(D[r] - mu*c1r[r]) + c2r[r];
    }
    __syncthreads();

    // ---------- phase B: attention on this 64-j tile, head h ----------
    f32x4 sc[4] = {};
    #pragma unroll
    for (int jb = 0; jb < 4; jb++)
      #pragma unroll
      for (int kh = 0; kh < 2; kh++) {
        bf16x8 bk = *(const bf16x8*)(kb + (size_t)(jt + jb*16 + jl)*1024 + h*64 + kh*32 + g*8);
        sc[jb] = MFMA16(bk, aq[kh], sc[jb]);   // swapped: rows=j, cols=q
      }
    #pragma unroll
    for (int jb = 0; jb < 4; jb++) {
      f32x4 bl = *(const f32x4*)(&biasT[h][jl][jb*16 + g*4]);
      sc[jb][0] += bl[0]; sc[jb][1] += bl[1];
      sc[jb][2] += bl[2]; sc[jb][3] += bl[3];
    }

    float mx = -1e30f;
    #pragma unroll
    for (int jb = 0; jb < 4; jb++)
      #pragma unroll
      for (int r = 0; r < 4; r++) mx = fmaxf(mx, sc[jb][r]);
    mx = fmaxf(mx, __shfl_xor(mx, 16));
    mx = fmaxf(mx, __shfl_xor(mx, 32));
    float mn = fmaxf(m, mx);
    float a = __expf(m - mn);
    m = mn;
    float rsum = 0.f;
    #pragma unroll
    for (int jb = 0; jb < 4; jb++) {
      short4 pk;
      float p0 = __expf(sc[jb][0] - mn); rsum += p0; pk.x = (short)f2bf(p0);
      float p1 = __expf(sc[jb][1] - mn); rsum += p1; pk.y = (short)f2bf(p1);
      float p2 = __expf(sc[jb][2] - mn); rsum += p2; pk.z = (short)f2bf(p2);
      float p3 = __expf(sc[jb][3] - mn); rsum += p3; pk.w = (short)f2bf(p3);
      int b = jb*2 + (g >> 1);
      int bpz = b ^ (jl & 7);
      *(short4*)(Pw + jl*64 + bpz*8 + (g & 1)*4) = pk;
    }
    ss = ss * a + rsum;   // per-lane quarter-partial (reduced over g at the end)

    float albc[4];
    #pragma unroll
    for (int r = 0; r < 4; r++) albc[r] = __shfl(a, g*4 + r);
    #pragma unroll
    for (int db = 0; db < 4; db++)
      #pragma unroll
      for (int r = 0; r < 4; r++) od[db][r] *= albc[r];

    #pragma unroll
    for (int jh = 0; jh < 2; jh++) {
      int b = jh*4 + g;
      int bpz = b ^ (jl & 7);
      bf16x8 ap = *(const bf16x8*)(Pw + jl*64 + bpz*8);
      #pragma unroll
      for (int db = 0; db < 4; db++) {
        bf16x8 bv = *(const bf16x8*)(vT + (size_t)(h*64 + db*16 + jl)*1024 + jt + jh*32 + g*8);
        od[db] = MFMA16(ap, bv, od[db]);
      }
    }
    __syncthreads();   // biasT reused next tile
  }

  // reduce ss across the 4 replicated lane-groups (same jl)
  ss += __shfl_xor(ss, 16);
  ss += __shfl_xor(ss, 32);

  size_t base = ((size_t)(s*16 + h) * 1024);
  #pragma unroll
  for (int db = 0; db < 4; db++)
    #pragma unroll
    for (int r = 0; r < 4; r++) {
      int q = q0 + g*4 + r;
      op[(base + q)*64 + db*16 + jl] = od[db][r];
    }
  if (g == 0) {
    ml[base + q0 + jl] = m;
    ll[base + q0 + jl] = ss;
  }
}

// ---------------- combine: merge 4 j-split partials, gate, bf16 (R10, unchanged) ------
__global__ __launch_bounds__(256) void combine_kernel(
    const float* __restrict__ op, const float* __restrict__ ml,
    const float* __restrict__ ll, const unsigned short* __restrict__ gb,
    unsigned short* __restrict__ og)
{
  int t = blockIdx.x * 256 + threadIdx.x;   // over 16h * 1024q * 16d4
  int d4 = t & 15;
  int q = (t >> 4) & 1023;
  int h = t >> 14;

  float mv[4], lv[4];
  float mstar = -1e30f;
  #pragma unroll
  for (int s = 0; s < 4; s++) {
    mv[s] = ml[(size_t)(s*16 + h)*1024 + q];
    lv[s] = ll[(size_t)(s*16 + h)*1024 + q];
    mstar = fmaxf(mstar, mv[s]);
  }
  float lsum = 0.f;
  float ws[4];
  #pragma unroll
  for (int s = 0; s < 4; s++) {
    ws[s] = __expf(mv[s] - mstar);
    lsum = fmaf(ws[s], lv[s], lsum);
  }
  float inv = 1.f / lsum;

  float4 o = {0.f, 0.f, 0.f, 0.f};
  #pragma unroll
  for (int s = 0; s < 4; s++) {
    float4 p = *(const float4*)(op + ((size_t)(s*16 + h)*1024 + q)*64 + d4*4);
    o.x = fmaf(ws[s], p.x, o.x); o.y = fmaf(ws[s], p.y, o.y);
    o.z = fmaf(ws[s], p.z, o.z); o.w = fmaf(ws[s], p.w, o.w);
  }
  ushort4 gv = *(const ushort4*)(gb + (size_t)q*1024 + h*64 + d4*4);
  ushort4 r;
  r.x = f2bf(o.x * inv * bf2f(gv.x));
  r.y = f2bf(o.y * inv * bf2f(gv.y));
  r.z = f2bf(o.z * inv * bf2f(gv.z));
  r.w = f2bf(o.w * inv * bf2f(gv.w));
  *(ushort4*)(og + (size_t)q*1024 + h*64 + d4*4) = r;
}

// ---------------- output GEMM: (o*g) @ wo^T, A bf16, B f32-direct (R6-proven) ---------
__global__ __launch_bounds__(256) void gemm_out(
    const unsigned short* __restrict__ A, const float* __restrict__ wo,
    float* __restrict__ outF)
{
  int lane = threadIdx.x & 63;
  int w = threadIdx.x >> 6;
  int lr = lane & 15, lg = lane >> 4;
  int row0 = blockIdx.y * 64 + (w & 1) * 32;
  int col0 = blockIdx.x * 128 + (w >> 1) * 64;
  f32x4 acc[2][4] = {};
  for (int kk = 0; kk < 1024; kk += 32) {
    bf16x8 af[2], bfr[4];
    #pragma unroll
    for (int t = 0; t < 2; t++)
      af[t] = *(const bf16x8*)(A + (size_t)(row0 + t*16 + lr)*1024 + kk + lg*8);
    #pragma unroll
    for (int t = 0; t < 4; t++) {
      const float* p = wo + (size_t)(col0 + t*16 + lr)*1024 + kk + lg*8;
      bfr[t] = cvt8(*(const float4*)p, *(const float4*)(p + 4));
    }
    #pragma unroll
    for (int a = 0; a < 2; a++)
      #pragma unroll
      for (int b = 0; b < 4; b++)
        acc[a][b] = MFMA16(af[a], bfr[b], acc[a][b]);
  }
  #pragma unroll
  for (int a = 0; a < 2; a++)
    #pragma unroll
    for (int b = 0; b < 4; b++)
      #pragma unroll
      for (int r = 0; r < 4; r++) {
        int m = row0 + a*16 + lg*4 + r;
        int n = col0 + b*16 + lr;
        outF[(size_t)m * 1024 + n] = acc[a][b][r];
      }
}

extern "C" void kernel_launch(void* const* d_in, const int* in_sizes, int n_in,
                              void* d_out, int out_size, void* d_ws, size_t ws_size,
                              hipStream_t stream) {
  const float* s   = (const float*)d_in[0];
  const float* z   = (const float*)d_in[1];
  const float* wq  = (const float*)d_in[2];
  const float* bq  = (const float*)d_in[3];
  const float* wk  = (const float*)d_in[4];
  const float* wv  = (const float*)d_in[5];
  const float* wg  = (const float*)d_in[6];
  const float* znw = (const float*)d_in[7];
  const float* znb = (const float*)d_in[8];
  const float* wz  = (const float*)d_in[9];
  const float* wo  = (const float*)d_in[10];
  float* out = (float*)d_out;

  char* ws = (char*)d_ws;
  unsigned short* qbuf  = (unsigned short*)(ws + ((size_t)64 << 20));  // 2 MB
  unsigned short* kbuf  = (unsigned short*)(ws + ((size_t)66 << 20));  // 2 MB
  unsigned short* vTb   = (unsigned short*)(ws + ((size_t)68 << 20));  // 2 MB
  unsigned short* gbuf  = (unsigned short*)(ws + ((size_t)70 << 20));  // 2 MB
  unsigned short* ogb   = (unsigned short*)(ws + ((size_t)72 << 20));  // 2 MB
  unsigned short* wzp   = (unsigned short*)(ws + ((size_t)86 << 20));  // 4 KB
  float*          c12   = (float*)(ws + ((size_t)86 << 20) + 4096);    // 128 B
  float*          opart = (float*)(ws + ((size_t)96 << 20));           // 16 MB
  float*          mlb   = (float*)(ws + ((size_t)112 << 20));          // 256 KB
  float*          llb   = (float*)(ws + ((size_t)113 << 20));          // 256 KB

  gemm_qkvg<<<dim3(33, 16), 256, 0, stream>>>(s, wq, wk, wv, wg, bq, wz, znw, znb,
                                              qbuf, kbuf, vTb, gbuf, wzp, c12);
  fused_attn<<<dim3(64, 4), 1024, 0, stream>>>(qbuf, kbuf, vTb, z, wzp, c12,
                                               opart, mlb, llb);
  combine_kernel<<<1024, 256, 0, stream>>>(opart, mlb, llb, gbuf, ogb);
  gemm_out<<<dim3(8, 16), 256, 0, stream>>>(ogb, wo, out);
}

// Round 13
// 265.431 us; speedup vs baseline: 1.1944x; 1.1944x over previous
//
#include <hip/hip_runtime.h>
#include <hip/hip_bf16.h>

typedef __attribute__((ext_vector_type(8))) short bf16x8;
typedef __attribute__((ext_vector_type(4))) float f32x4;

#define MFMA16(a,b,c) __builtin_amdgcn_mfma_f32_16x16x32_bf16(a,b,c,0,0,0)

__device__ __forceinline__ unsigned short f2bf(float f){
  __hip_bfloat16 h = __float2bfloat16(f);
  unsigned short r;
  __builtin_memcpy(&r, &h, 2);
  return r;
}
__device__ __forceinline__ float bf2f(unsigned short u){
  return __uint_as_float(((unsigned int)u) << 16);
}
__device__ __forceinline__ bf16x8 cvt8(float4 a, float4 b){
  bf16x8 t;
  t[0] = (short)f2bf(a.x); t[1] = (short)f2bf(a.y);
  t[2] = (short)f2bf(a.z); t[3] = (short)f2bf(a.w);
  t[4] = (short)f2bf(b.x); t[5] = (short)f2bf(b.y);
  t[6] = (short)f2bf(b.z); t[7] = (short)f2bf(b.w);
  return t;
}

// ---------------- prep: f32 -> bf16 conversions (+ embedded wz prep) ----------------
__global__ __launch_bounds__(256) void prep_kernel(
    const float* __restrict__ s, const float* __restrict__ wq,
    const float* __restrict__ wk, const float* __restrict__ wv,
    const float* __restrict__ wg, const float* __restrict__ wo,
    const float* __restrict__ wz, const float* __restrict__ znw,
    const float* __restrict__ znb,
    unsigned short* __restrict__ sb, unsigned short* __restrict__ Wp,
    unsigned short* __restrict__ wob,
    unsigned short* __restrict__ wzp, float* __restrict__ c12)
{
  __shared__ float r1[256], r2[256];
  if (blockIdx.x == 6144) {
    int t = threadIdx.x; int h = t >> 4; int k0 = (t & 15) * 8;
    float p1 = 0.f, p2 = 0.f;
    for (int e = 0; e < 8; e++) {
      float wvv = wz[h*128 + k0 + e];
      float w = znw[k0 + e], b = znb[k0 + e];
      wzp[h*128 + k0 + e] = f2bf(wvv * w);
      p1 += wvv * w; p2 += wvv * b;
    }
    r1[t] = p1; r2[t] = p2;
    __syncthreads();
    if ((t & 15) == 0) {
      float s1 = 0.f, s2 = 0.f;
      for (int i = 0; i < 16; i++) { s1 += r1[t + i]; s2 += r2[t + i]; }
      c12[2*h] = s1; c12[2*h + 1] = s2;
    }
    return;
  }
  const size_t M1 = 1u << 20;
  size_t base = ((size_t)blockIdx.x * 256 + threadIdx.x) * 4;
  const float* src; unsigned short* dst; size_t off;
  if (base < M1) { src = s; dst = sb; off = base; }
  else if (base < 5*M1) {
    size_t r = base - M1; int wsel = (int)(r >> 20);
    const float* wsrc0 = (wsel == 0) ? wq : (wsel == 1) ? wk : (wsel == 2) ? wv : wg;
    src = wsrc0; dst = Wp + ((size_t)wsel << 20); off = r & (M1 - 1);
  } else { src = wo; dst = wob; off = base - 5*M1; }
  float4 v = *(const float4*)(src + off);
  ushort4 o4;
  o4.x = f2bf(v.x); o4.y = f2bf(v.y); o4.z = f2bf(v.z); o4.w = f2bf(v.w);
  *(ushort4*)(dst + off) = o4;
}

// ---------------- mega1: role-split — qkvg GEMM (bid<512) + bias stream (bid>=512) ----
// Bias role: fully wave-independent (NO barriers, NO LDS). Per wave: 16 units of
// (q-row i, 16 j's); 3-buffer register rotation keeps 2 chunks (2 KB) in flight
// per wave at all times -> ~24 KB/CU outstanding, saturating HBM. Bias written
// directly per-lane (scattered ushort, 32B sectors/16-lane group) — no bounce.
__global__ __launch_bounds__(256) void mega1(
    const float* __restrict__ z, const unsigned short* __restrict__ wzp,
    const float* __restrict__ c12, unsigned short* __restrict__ bias,
    const unsigned short* __restrict__ sb, const unsigned short* __restrict__ Wp,
    const float* __restrict__ bq,
    unsigned short* __restrict__ qb, unsigned short* __restrict__ kb,
    unsigned short* __restrict__ vT, unsigned short* __restrict__ gb)
{
  int lane = threadIdx.x & 63;
  int w = threadIdx.x >> 6;
  int jl = lane & 15, g = lane >> 4;

  if (blockIdx.x < 512) {
    // ---------------- qkvg GEMM role (R5-proven body) ----------------
    int bx = blockIdx.x & 31, by = blockIdx.x >> 5;
    int lr = jl, lg = g;
    int row0 = by * 64 + (w & 1) * 32;
    int col0 = bx * 128 + (w >> 1) * 64;
    f32x4 acc[2][4] = {};
    for (int kk = 0; kk < 1024; kk += 32) {
      bf16x8 afr[2], bfr[4];
      #pragma unroll
      for (int t = 0; t < 2; t++)
        afr[t] = *(const bf16x8*)(sb + (size_t)(row0 + t*16 + lr)*1024 + kk + lg*8);
      #pragma unroll
      for (int t = 0; t < 4; t++)
        bfr[t] = *(const bf16x8*)(Wp + (size_t)(col0 + t*16 + lr)*1024 + kk + lg*8);
      #pragma unroll
      for (int a = 0; a < 2; a++)
        #pragma unroll
        for (int b = 0; b < 4; b++)
          acc[a][b] = MFMA16(afr[a], bfr[b], acc[a][b]);
    }
    #pragma unroll
    for (int a = 0; a < 2; a++)
      #pragma unroll
      for (int b = 0; b < 4; b++)
        #pragma unroll
        for (int r = 0; r < 4; r++) {
          int m = row0 + a*16 + lg*4 + r;
          int n = col0 + b*16 + lr;
          float v = acc[a][b][r];
          if (n < 1024)      { v = (v + bq[n]) * 0.125f; qb[(size_t)m*1024 + n] = f2bf(v); }
          else if (n < 2048) { kb[(size_t)m*1024 + (n-1024)] = f2bf(v); }
          else if (n < 3072) { vT[(size_t)(n-2048)*1024 + m] = f2bf(v); }
          else               { float sg = 1.f / (1.f + __expf(-v)); gb[(size_t)m*1024 + (n-3072)] = f2bf(sg); }
        }
    return;
  }

  // ---------------- bias stream role ----------------
  bf16x8 af[4];
  #pragma unroll
  for (int mk = 0; mk < 4; mk++)
    af[mk] = *(const bf16x8*)(wzp + jl*128 + mk*32 + g*8);
  float c1r[4], c2r[4];
  #pragma unroll
  for (int r = 0; r < 4; r++) {
    c1r[r] = c12[2*(g*4 + r)];
    c2r[r] = c12[2*(g*4 + r) + 1];
  }

  int W = (blockIdx.x - 512) * 4 + w;   // 0..4095
  int u0 = W * 16;                      // unit u = i*64 + j16; 16 units/wave

  float4 RA[8], RB[8], RC[8];

  auto loadu = [&](int k, float4 (&R)[8]) {
    int u = u0 + k;
    const float* zp = z + ((size_t)(u >> 6)*1024 + (u & 63)*16 + jl)*128 + g*8;
    #pragma unroll
    for (int mk = 0; mk < 4; mk++) {
      R[2*mk]   = *(const float4*)(zp + mk*32);
      R[2*mk+1] = *(const float4*)(zp + mk*32 + 4);
    }
  };
  auto procu = [&](int k, float4 (&A)[8]) {
    int u = u0 + k;
    float sum = 0.f, sq = 0.f;
    #pragma unroll
    for (int q = 0; q < 8; q++) {
      float4 v = A[q];
      sum += v.x + v.y + v.z + v.w;
      sq = fmaf(v.x, v.x, fmaf(v.y, v.y, fmaf(v.z, v.z, fmaf(v.w, v.w, sq))));
    }
    sum += __shfl_xor(sum, 16); sum += __shfl_xor(sum, 32);
    sq  += __shfl_xor(sq, 16);  sq  += __shfl_xor(sq, 32);
    float mu = sum * (1.f/128.f);
    float rs = rsqrtf(sq * (1.f/128.f) - mu*mu + 1e-5f);
    f32x4 D = {0.f, 0.f, 0.f, 0.f};
    #pragma unroll
    for (int mk = 0; mk < 4; mk++)
      D = MFMA16(af[mk], cvt8(A[2*mk], A[2*mk+1]), D);
    size_t jaddr = (size_t)(u >> 6)*1024 + (u & 63)*16 + jl;
    #pragma unroll
    for (int r = 0; r < 4; r++)
      bias[((size_t)(g*4 + r) << 20) + jaddr] =
          f2bf(rs*(D[r] - mu*c1r[r]) + c2r[r]);
  };

  loadu(0, RA);
  loadu(1, RB);
  #pragma unroll 1
  for (int k = 0; k < 15; k += 3) {
    if (k + 2 < 16) loadu(k + 2, RC);
    procu(k, RA);
    if (k + 3 < 16) loadu(k + 3, RA);
    procu(k + 1, RB);
    if (k + 4 < 16) loadu(k + 4, RB);
    if (k + 2 < 16) procu(k + 2, RC);
  }
  procu(15, RA);
}

// ---------------- attention: swapped-QK^T flash, 4-way j-split, bf16 bias (R8) --------
__global__ __launch_bounds__(256) void attn_kernel(
    const unsigned short* __restrict__ qb, const unsigned short* __restrict__ kb,
    const unsigned short* __restrict__ vT, const unsigned short* __restrict__ bias,
    float* __restrict__ op, float* __restrict__ ml, float* __restrict__ ll)
{
  __shared__ unsigned short P[4][1024];
  int lane = threadIdx.x & 63;
  int s = threadIdx.x >> 6;
  int jl = lane & 15, g = lane >> 4;
  int q0 = blockIdx.x * 16;
  int h = blockIdx.y;
  unsigned short* Pw = P[s];

  bf16x8 aq[2];
  #pragma unroll
  for (int kh = 0; kh < 2; kh++)
    aq[kh] = *(const bf16x8*)(qb + (size_t)(q0 + jl)*1024 + h*64 + kh*32 + g*8);

  f32x4 od[4] = {};
  float m = -1e30f, ss = 0.f;
  const unsigned short* bp = bias + ((size_t)h << 20);

  for (int jt = s*256; jt < s*256 + 256; jt += 64) {
    f32x4 sc[4] = {};
    #pragma unroll
    for (int jb = 0; jb < 4; jb++)
      #pragma unroll
      for (int kh = 0; kh < 2; kh++) {
        bf16x8 bk = *(const bf16x8*)(kb + (size_t)(jt + jb*16 + jl)*1024 + h*64 + kh*32 + g*8);
        sc[jb] = MFMA16(bk, aq[kh], sc[jb]);
      }
    #pragma unroll
    for (int jb = 0; jb < 4; jb++) {
      ushort4 bl = *(const ushort4*)(bp + (size_t)(q0 + jl)*1024 + jt + jb*16 + g*4);
      sc[jb][0] += bf2f(bl.x); sc[jb][1] += bf2f(bl.y);
      sc[jb][2] += bf2f(bl.z); sc[jb][3] += bf2f(bl.w);
    }

    float mx = -1e30f;
    #pragma unroll
    for (int jb = 0; jb < 4; jb++)
      #pragma unroll
      for (int r = 0; r < 4; r++) mx = fmaxf(mx, sc[jb][r]);
    mx = fmaxf(mx, __shfl_xor(mx, 16));
    mx = fmaxf(mx, __shfl_xor(mx, 32));
    float mn = fmaxf(m, mx);
    float a = __expf(m - mn);
    m = mn;
    float rsum = 0.f;
    #pragma unroll
    for (int jb = 0; jb < 4; jb++) {
      short4 pk;
      float p0 = __expf(sc[jb][0] - mn); rsum += p0; pk.x = (short)f2bf(p0);
      float p1 = __expf(sc[jb][1] - mn); rsum += p1; pk.y = (short)f2bf(p1);
      float p2 = __expf(sc[jb][2] - mn); rsum += p2; pk.z = (short)f2bf(p2);
      float p3 = __expf(sc[jb][3] - mn); rsum += p3; pk.w = (short)f2bf(p3);
      int b = jb*2 + (g >> 1);
      int bpz = b ^ (jl & 7);
      *(short4*)(Pw + jl*64 + bpz*8 + (g & 1)*4) = pk;
    }
    ss = ss * a + rsum;

    float albc[4];
    #pragma unroll
    for (int r = 0; r < 4; r++) albc[r] = __shfl(a, g*4 + r);
    #pragma unroll
    for (int db = 0; db < 4; db++)
      #pragma unroll
      for (int r = 0; r < 4; r++) od[db][r] *= albc[r];

    #pragma unroll
    for (int jh = 0; jh < 2; jh++) {
      int b = jh*4 + g;
      int bpz = b ^ (jl & 7);
      bf16x8 ap = *(const bf16x8*)(Pw + jl*64 + bpz*8);
      #pragma unroll
      for (int db = 0; db < 4; db++) {
        bf16x8 bv = *(const bf16x8*)(vT + (size_t)(h*64 + db*16 + jl)*1024 + jt + jh*32 + g*8);
        od[db] = MFMA16(ap, bv, od[db]);
      }
    }
  }

  ss += __shfl_xor(ss, 16);
  ss += __shfl_xor(ss, 32);

  size_t base = ((size_t)(s*16 + h) * 1024);
  #pragma unroll
  for (int db = 0; db < 4; db++)
    #pragma unroll
    for (int r = 0; r < 4; r++) {
      int q = q0 + g*4 + r;
      op[(base + q)*64 + db*16 + jl] = od[db][r];
    }
  if (g == 0) {
    ml[base + q0 + jl] = m;
    ll[base + q0 + jl] = ss;
  }
}

// ---------------- combine: merge 4 j-split partials, gate, bf16 ----------------
__global__ __launch_bounds__(256) void combine_kernel(
    const float* __restrict__ op, const float* __restrict__ ml,
    const float* __restrict__ ll, const unsigned short* __restrict__ gb,
    unsigned short* __restrict__ og)
{
  int t = blockIdx.x * 256 + threadIdx.x;
  int d4 = t & 15;
  int q = (t >> 4) & 1023;
  int h = t >> 14;

  float mv[4], lv[4];
  float mstar = -1e30f;
  #pragma unroll
  for (int s = 0; s < 4; s++) {
    mv[s] = ml[(size_t)(s*16 + h)*1024 + q];
    lv[s] = ll[(size_t)(s*16 + h)*1024 + q];
    mstar = fmaxf(mstar, mv[s]);
  }
  float lsum = 0.f;
  float ws[4];
  #pragma unroll
  for (int s = 0; s < 4; s++) {
    ws[s] = __expf(mv[s] - mstar);
    lsum = fmaf(ws[s], lv[s], lsum);
  }
  float inv = 1.f / lsum;

  float4 o = {0.f, 0.f, 0.f, 0.f};
  #pragma unroll
  for (int s = 0; s < 4; s++) {
    float4 p = *(const float4*)(op + ((size_t)(s*16 + h)*1024 + q)*64 + d4*4);
    o.x = fmaf(ws[s], p.x, o.x); o.y = fmaf(ws[s], p.y, o.y);
    o.z = fmaf(ws[s], p.z, o.z); o.w = fmaf(ws[s], p.w, o.w);
  }
  ushort4 gv = *(const ushort4*)(gb + (size_t)q*1024 + h*64 + d4*4);
  ushort4 r;
  r.x = f2bf(o.x * inv * bf2f(gv.x));
  r.y = f2bf(o.y * inv * bf2f(gv.y));
  r.z = f2bf(o.z * inv * bf2f(gv.z));
  r.w = f2bf(o.w * inv * bf2f(gv.w));
  *(ushort4*)(og + (size_t)q*1024 + h*64 + d4*4) = r;
}

// ---------------- output GEMM: (o*g) @ wo^T -> f32 (bf16 operands) ----------------
__global__ __launch_bounds__(256) void gemm_out(
    const unsigned short* __restrict__ A, const unsigned short* __restrict__ Bm,
    float* __restrict__ outF)
{
  int lane = threadIdx.x & 63;
  int w = threadIdx.x >> 6;
  int lr = lane & 15, lg = lane >> 4;
  int row0 = blockIdx.y * 64 + (w & 1) * 32;
  int col0 = blockIdx.x * 128 + (w >> 1) * 64;
  f32x4 acc[2][4] = {};
  for (int kk = 0; kk < 1024; kk += 32) {
    bf16x8 af[2], bfr[4];
    #pragma unroll
    for (int t = 0; t < 2; t++)
      af[t] = *(const bf16x8*)(A + (size_t)(row0 + t*16 + lr)*1024 + kk + lg*8);
    #pragma unroll
    for (int t = 0; t < 4; t++)
      bfr[t] = *(const bf16x8*)(Bm + (size_t)(col0 + t*16 + lr)*1024 + kk + lg*8);
    #pragma unroll
    for (int a = 0; a < 2; a++)
      #pragma unroll
      for (int b = 0; b < 4; b++)
        acc[a][b] = MFMA16(af[a], bfr[b], acc[a][b]);
  }
  #pragma unroll
  for (int a = 0; a < 2; a++)
    #pragma unroll
    for (int b = 0; b < 4; b++)
      #pragma unroll
      for (int r = 0; r < 4; r++) {
        int m = row0 + a*16 + lg*4 + r;
        int n = col0 + b*16 + lr;
        outF[(size_t)m * 1024 + n] = acc[a][b][r];
      }
}

extern "C" void kernel_launch(void* const* d_in, const int* in_sizes, int n_in,
                              void* d_out, int out_size, void* d_ws, size_t ws_size,
                              hipStream_t stream) {
  const float* s   = (const float*)d_in[0];
  const float* z   = (const float*)d_in[1];
  const float* wq  = (const float*)d_in[2];
  const float* bq  = (const float*)d_in[3];
  const float* wk  = (const float*)d_in[4];
  const float* wv  = (const float*)d_in[5];
  const float* wg  = (const float*)d_in[6];
  const float* znw = (const float*)d_in[7];
  const float* znb = (const float*)d_in[8];
  const float* wz  = (const float*)d_in[9];
  const float* wo  = (const float*)d_in[10];
  float* out = (float*)d_out;

  char* ws = (char*)d_ws;
  unsigned short* biasb = (unsigned short*)ws;                         // 32 MB (bf16)
  unsigned short* qbuf  = (unsigned short*)(ws + ((size_t)64 << 20));  // 2 MB
  unsigned short* kbuf  = (unsigned short*)(ws + ((size_t)66 << 20));  // 2 MB
  unsigned short* vTb   = (unsigned short*)(ws + ((size_t)68 << 20));  // 2 MB
  unsigned short* gbuf  = (unsigned short*)(ws + ((size_t)70 << 20));  // 2 MB
  unsigned short* ogb   = (unsigned short*)(ws + ((size_t)72 << 20));  // 2 MB
  unsigned short* sb    = (unsigned short*)(ws + ((size_t)74 << 20));  // 2 MB
  unsigned short* Wp    = (unsigned short*)(ws + ((size_t)76 << 20));  // 8 MB
  unsigned short* wob   = (unsigned short*)(ws + ((size_t)84 << 20));  // 2 MB
  unsigned short* wzp   = (unsigned short*)(ws + ((size_t)86 << 20));  // 4 KB
  float*          c12   = (float*)(ws + ((size_t)86 << 20) + 4096);    // 128 B
  float*          opart = (float*)(ws + ((size_t)96 << 20));           // 16 MB
  float*          mlb   = (float*)(ws + ((size_t)112 << 20));          // 256 KB
  float*          llb   = (float*)(ws + ((size_t)113 << 20));          // 256 KB

  prep_kernel<<<6145, 256, 0, stream>>>(s, wq, wk, wv, wg, wo, wz, znw, znb,
                                        sb, Wp, wob, wzp, c12);
  mega1<<<1536, 256, 0, stream>>>(z, wzp, c12, biasb,
                                  sb, Wp, bq, qbuf, kbuf, vTb, gbuf);
  attn_kernel<<<dim3(64, 16), 256, 0, stream>>>(qbuf, kbuf, vTb, biasb, opart, mlb, llb);
  combine_kernel<<<1024, 256, 0, stream>>>(opart, mlb, llb, gbuf, ogb);
  gemm_out<<<dim3(8, 16), 256, 0, stream>>>(ogb, wob, out);
}